// Round 1
// baseline (412.397 us; speedup 1.0000x reference)
//
#include <hip/hip_runtime.h>

#define N_NODES   100000
#define N_EDGES   1600000
#define N_GRAPHS  128
#define HIDDEN    128
#define N_CLASSES 10

typedef unsigned int   uint;
typedef unsigned short ushort;

// ---------------- K1: degree count (3.2M u32 atomics, L2-resident arrays) ----
__global__ __launch_bounds__(256)
void k_deg(const int4* __restrict__ src4, const int4* __restrict__ dst4,
           uint* __restrict__ indeg, uint* __restrict__ outdeg, int nE4) {
    int i = blockIdx.x * 256 + threadIdx.x;
    if (i >= nE4) return;
    int4 s = src4[i], d = dst4[i];
    atomicAdd(&outdeg[s.x], 1u); atomicAdd(&outdeg[s.y], 1u);
    atomicAdd(&outdeg[s.z], 1u); atomicAdd(&outdeg[s.w], 1u);
    atomicAdd(&indeg[d.x], 1u);  atomicAdd(&indeg[d.y], 1u);
    atomicAdd(&indeg[d.z], 1u);  atomicAdd(&indeg[d.w], 1u);
}

// ---------------- K2: per-block scan of indeg -> row starts (order-free base),
//                  plus ns / hs0 / rsind / cur init. 98 blocks x 1024. --------
__global__ __launch_bounds__(1024)
void k_scan(const uint* __restrict__ indeg, const uint* __restrict__ outdeg,
            uint* __restrict__ etotal, uint* __restrict__ cur,
            uint* __restrict__ rsind, float* __restrict__ ns,
            float* __restrict__ hs0, int nN) {
    __shared__ uint sc[1024];
    __shared__ uint sbase;
    int t = threadIdx.x;
    int n = blockIdx.x * 1024 + t;
    uint v = (n < nN) ? indeg[n] : 0u;
    sc[t] = v;
    __syncthreads();
    for (int off = 1; off < 1024; off <<= 1) {
        uint add = (t >= off) ? sc[t - off] : 0u;
        __syncthreads();
        sc[t] += add;
        __syncthreads();
    }
    if (t == 1023) sbase = atomicAdd(etotal, sc[1023]);
    __syncthreads();
    if (n < nN) {
        uint incl = sc[t];
        uint row  = sbase + incl - v;          // exclusive within block + block base
        uint od   = outdeg[n];
        float nsv = rsqrtf(fmaxf((float)od, 1.0f));
        ns[n]    = nsv;
        hs0[n]   = (float)v * nsv;             // h0 = indeg ; hs0 = h0 * norm_src
        cur[n]   = row;
        rsind[n] = (row << 10) | min(v, 1023u);
    }
}

// ---------------- K3: CSR fill + fused conv1 aggregation ---------------------
//   per edge: csr[atomicAdd(cur[dst])] = src ; agg1[dst] += hs0[src]
__global__ __launch_bounds__(256)
void k_fill(const int4* __restrict__ src4, const int4* __restrict__ dst4,
            const float* __restrict__ hs0, uint* __restrict__ cur,
            int* __restrict__ csr, float* __restrict__ agg1, int nE4) {
    int i = blockIdx.x * 256 + threadIdx.x;
    if (i >= nE4) return;
    int4 s = src4[i], d = dst4[i];
    float h0 = hs0[s.x], h1 = hs0[s.y], h2 = hs0[s.z], h3 = hs0[s.w];
    uint p0 = atomicAdd(&cur[d.x], 1u);
    uint p1 = atomicAdd(&cur[d.y], 1u);
    uint p2 = atomicAdd(&cur[d.z], 1u);
    uint p3 = atomicAdd(&cur[d.w], 1u);
    csr[p0] = s.x; csr[p1] = s.y; csr[p2] = s.z; csr[p3] = s.w;
    atomicAdd(&agg1[d.x], h0); atomicAdd(&agg1[d.y], h1);
    atomicAdd(&agg1[d.z], h2); atomicAdd(&agg1[d.w], h3);
}

// ---------------- K4: pure node pass: av, segment id, info; U/V table --------
__global__ __launch_bounds__(256)
void k_info(const uint* __restrict__ indeg, const float* __restrict__ agg1,
            const float* __restrict__ ns,
            const float* __restrict__ W1, const float* __restrict__ b1,
            const float* __restrict__ W2,
            float* __restrict__ U, float* __restrict__ V,
            float4* __restrict__ info, int nN) {
    __shared__ float stu[128];        // unsorted breakpoints
    __shared__ float sts[128];        // sorted (blocks < 129 only)
    int t = threadIdx.x;
    if (t < 128) {
        float w = W1[t], bb = b1[t];
        stu[t] = (w != 0.0f) ? (-bb / w) : 1e30f;
    }
    __syncthreads();
    if (blockIdx.x < 129) {           // block-uniform branch: syncs are legal
        if (t < 128) sts[t] = stu[t];
        __syncthreads();
        for (int k = 2; k <= 128; k <<= 1) {
            for (int j = k >> 1; j > 0; j >>= 1) {
                if (t < 128) {
                    int ixj = t ^ j;
                    if (ixj > t) {
                        float a = sts[t], bb = sts[ixj];
                        bool up = ((t & k) == 0);
                        if (up ? (a > bb) : (a < bb)) { sts[t] = bb; sts[ixj] = a; }
                    }
                }
                __syncthreads();
            }
        }
        if (t < 128) {                // segment-table row, unconditional W2 loads
            int sg = blockIdx.x;
            float a_rep;
            if (sg == 0)        a_rep = sts[0]   - 1.0f;
            else if (sg == 128) a_rep = sts[127] + 1.0f;
            else                a_rep = 0.5f * (sts[sg - 1] + sts[sg]);
            float u = 0.0f, vv = 0.0f;
            #pragma unroll 8
            for (int j = 0; j < 128; ++j) {
                float w  = W1[j], bb = b1[j];
                float w2 = W2[j * HIDDEN + t];
                bool on  = (a_rep * w + bb > 0.0f);
                u  += on ? w  * w2 : 0.0f;
                vv += on ? bb * w2 : 0.0f;
            }
            U[sg * HIDDEN + t] = u;
            V[sg * HIDDEN + t] = vv;
        }
    }
    int node = blockIdx.x * 256 + t;
    if (node >= nN) return;
    uint c   = indeg[node];
    float nd = rsqrtf(fmaxf((float)c, 1.0f));
    float av = agg1[node] * nd;
    int sgp = 0;
    #pragma unroll 16
    for (int q = 0; q < 128; ++q) sgp += (stu[q] < av) ? 1 : 0;
    float nsv = ns[node];
    info[node] = make_float4(nsv * av, nsv, __int_as_float(sgp), nd);
}

// ---- conv2: 4 threads/node register gather (shuffle combine); then ALL 4 waves
//      compute relu rows (16 nodes each) into LDS; wave 0 pools from LDS.
__global__ __launch_bounds__(256)
void k_conv2_pool(const uint* __restrict__ rsind, const int* __restrict__ csr,
                  const float4* __restrict__ info,
                  const float* __restrict__ U, const float* __restrict__ V,
                  const int* __restrict__ graph_ids, const float* __restrict__ b2,
                  float* __restrict__ pool, float* __restrict__ cnt, int nN) {
    __shared__ float sA[64], sB[64], sND[64];
    __shared__ int   sSg[64], sGr[64], sR[64], sC[64];
    __shared__ float sRes[64][HIDDEN];          // 32 KB relu'd rows
    int blockBase = blockIdx.x * 64;
    int t = threadIdx.x;
    int node = blockBase + (t >> 2);
    int j = t & 3;

    float A = 0.0f, B = 0.0f;
    int mn = 255, mx = 0;
    int r0 = 0, c = 0;
    if (node < nN) {
        uint rix = rsind[node];
        r0 = (int)(rix >> 10); c = (int)(rix & 1023u);
        #pragma unroll 4
        for (int k = j; k < c; k += 4) {
            float4 nf = info[csr[r0 + k]];
            int sg = __float_as_int(nf.z);
            A += nf.x; B += nf.y;
            mn = min(mn, sg); mx = max(mx, sg);
        }
    }
    A += __shfl_xor(A, 1); A += __shfl_xor(A, 2);
    B += __shfl_xor(B, 1); B += __shfl_xor(B, 2);
    mn = min(mn, __shfl_xor(mn, 1)); mn = min(mn, __shfl_xor(mn, 2));
    mx = max(mx, __shfl_xor(mx, 1)); mx = max(mx, __shfl_xor(mx, 2));
    if (node < nN && j == 0) {
        int i = t >> 2;
        sA[i] = A; sB[i] = B;
        sSg[i] = (mn << 8) | mx;
        sR[i] = r0; sC[i] = c;
        sND[i] = info[node].w;
        sGr[i] = graph_ids[node];
    }
    __syncthreads();

    // phase 2a: all 4 waves compute relu rows (16 nodes each) -> LDS
    int w = t >> 6, lane = t & 63;
    float bb0 = b2[lane], bb1 = b2[64 + lane];
    for (int i = w * 16; i < w * 16 + 16; ++i) {
        int n = blockBase + i;
        if (n >= nN) break;
        int pk = sSg[i], smn = pk >> 8, smx = pk & 255;
        float acc0, acc1;
        if (smn >= smx) {                      // uniform segment (or no edges)
            int sg = min(smn, 128);
            float Av = sA[i], Bv = sB[i];
            const float* Ur = U + sg * HIDDEN;
            const float* Vr = V + sg * HIDDEN;
            acc0 = Av * Ur[lane]      + Bv * Vr[lane];
            acc1 = Av * Ur[64 + lane] + Bv * Vr[64 + lane];
        } else {                               // mixed: exact per-node rescan (rare)
            acc0 = 0.0f; acc1 = 0.0f;
            int rr = sR[i], cc = sC[i];
            for (int k = 0; k < cc; ++k) {
                float4 nf = info[csr[rr + k]];
                int sg = __float_as_int(nf.z);
                const float* Ur = U + sg * HIDDEN;
                const float* Vr = V + sg * HIDDEN;
                acc0 += nf.x * Ur[lane]      + nf.y * Vr[lane];
                acc1 += nf.x * Ur[64 + lane] + nf.y * Vr[64 + lane];
            }
        }
        float nd = sND[i];
        sRes[i][lane]      = fmaxf(nd * acc0 + bb0, 0.0f);
        sRes[i][64 + lane] = fmaxf(nd * acc1 + bb1, 0.0f);
    }
    __syncthreads();

    // phase 2b: wave 0 pools from LDS (sorted graph_ids -> few flushes)
    if (t >= 64) return;
    int lane0 = t;
    int gcur = -1;
    float racc0 = 0.0f, racc1 = 0.0f, cl = 0.0f;
    for (int i = 0; i < 64; ++i) {
        int n = blockBase + i;
        if (n >= nN) break;
        float r0v = sRes[i][lane0];
        float r1v = sRes[i][64 + lane0];
        int g = sGr[i];
        if (g != gcur) {
            if (gcur >= 0) {
                atomicAdd(&pool[gcur * HIDDEN + lane0],      racc0);
                atomicAdd(&pool[gcur * HIDDEN + 64 + lane0], racc1);
                if (lane0 == 0) atomicAdd(&cnt[gcur], cl);
            }
            gcur = g; racc0 = 0.0f; racc1 = 0.0f; cl = 0.0f;
        }
        racc0 += r0v; racc1 += r1v; cl += 1.0f;
    }
    if (gcur >= 0) {
        atomicAdd(&pool[gcur * HIDDEN + lane0],      racc0);
        atomicAdd(&pool[gcur * HIDDEN + 64 + lane0], racc1);
        if (lane0 == 0) atomicAdd(&cnt[gcur], cl);
    }
}

// ----------------------------------------------- classifier head (tiny)
__global__ void k_final(const float* __restrict__ pool, const float* __restrict__ cnt,
                        const float* __restrict__ Wc, const float* __restrict__ bc,
                        float* __restrict__ out) {
    int t = blockIdx.x * blockDim.x + threadIdx.x;
    if (t >= N_GRAPHS * N_CLASSES) return;
    int g = t / N_CLASSES, c = t % N_CLASSES;
    float inv = 1.0f / fmaxf(cnt[g], 1.0f);
    float acc = bc[c];
    for (int j = 0; j < HIDDEN; ++j)
        acc += pool[g * HIDDEN + j] * inv * Wc[j * N_CLASSES + c];
    out[t] = acc;
}

extern "C" void kernel_launch(void* const* d_in, const int* in_sizes, int n_in,
                              void* d_out, int out_size, void* d_ws, size_t ws_size,
                              hipStream_t stream) {
    const int*   src       = (const int*)d_in[0];
    const int*   dst       = (const int*)d_in[1];
    const int*   graph_ids = (const int*)d_in[2];
    const float* W1        = (const float*)d_in[3];
    const float* b1        = (const float*)d_in[4];
    const float* W2        = (const float*)d_in[5];
    const float* b2        = (const float*)d_in[6];
    const float* Wc        = (const float*)d_in[7];
    const float* bc        = (const float*)d_in[8];
    float* out = (float*)d_out;

    char* ws = (char*)d_ws;
    size_t off = 0;
    auto alloc = [&](size_t elems) { void* p = ws + off; off += elems * 4; return p; };

    // --- zeroed region (single small memset) ---
    uint*  indeg  = (uint*) alloc(N_NODES);                 // 400 KB
    uint*  outdeg = (uint*) alloc(N_NODES);                 // 400 KB
    float* agg1   = (float*)alloc(N_NODES);                 // 400 KB
    float* pool   = (float*)alloc(N_GRAPHS * HIDDEN);       // 64 KB
    float* cnt    = (float*)alloc(N_GRAPHS);                // 512 B
    uint*  etotal = (uint*) alloc(4);                       // 16 B
    size_t zero_bytes = off;                                // ~1.27 MB
    // --- non-zeroed ---
    uint*   cur   = (uint*)  alloc(N_NODES);
    uint*   rsind = (uint*)  alloc(N_NODES);
    float*  nsA   = (float*) alloc(N_NODES);
    float*  hs0   = (float*) alloc(N_NODES);
    float4* info  = (float4*)alloc((size_t)N_NODES * 4);    // 1.6 MB
    int*    csr   = (int*)   alloc((size_t)N_EDGES);        // 6.4 MB exact
    float*  U     = (float*) alloc(129 * HIDDEN);
    float*  V     = (float*) alloc(129 * HIDDEN);

    hipMemsetAsync(d_ws, 0, zero_bytes, stream);

    int nE4      = N_EDGES / 4;                       // 400000 (divisible)
    int eblocks  = (nE4 + 255) / 256;                 // 1563
    int sblocks  = (N_NODES + 1023) / 1024;           // 98
    int iblocks  = (N_NODES + 255) / 256;             // 391
    int c2blocks = (N_NODES + 63) / 64;               // 1563

    k_deg       <<<eblocks, 256, 0, stream>>>((const int4*)src, (const int4*)dst,
                                              indeg, outdeg, nE4);
    k_scan      <<<sblocks, 1024, 0, stream>>>(indeg, outdeg, etotal, cur,
                                               rsind, nsA, hs0, N_NODES);
    k_fill      <<<eblocks, 256, 0, stream>>>((const int4*)src, (const int4*)dst,
                                              hs0, cur, csr, agg1, nE4);
    k_info      <<<iblocks, 256, 0, stream>>>(indeg, agg1, nsA, W1, b1, W2,
                                              U, V, info, N_NODES);
    k_conv2_pool<<<c2blocks, 256, 0, stream>>>(rsind, csr, info, U, V,
                                               graph_ids, b2, pool, cnt, N_NODES);
    k_final     <<<(N_GRAPHS * N_CLASSES + 255) / 256, 256, 0, stream>>>(pool, cnt, Wc, bc, out);
}

// Round 2
// 190.349 us; speedup vs baseline: 2.1665x; 2.1665x over previous
//
#include <hip/hip_runtime.h>

#define N_NODES   100000
#define N_EDGES   1600000
#define N_GRAPHS  128
#define HIDDEN    128
#define N_CLASSES 10

#define BSH   9                   // bucket = 512 nodes
#define BSZ   512
#define NBUCK 196                 // ceil(100000/512)
#define CAP   16384               // mean fill 8192
#define PCH   4096                // edges per partition block
#define PTH   512                 // partition threads
#define PIT   (PCH / PTH)         // 8 edges cached per thread

typedef unsigned int   uint;
typedef unsigned short ushort;
typedef unsigned char  uchar;

// -------- partition, two sequential phases sharing one staging buffer;
//          src/dst register-cached across phases (verified round-0 kernel).
__global__ __launch_bounds__(PTH)
void k_part(const int* __restrict__ src, const int* __restrict__ dst,
            unsigned* __restrict__ bcur1, unsigned* __restrict__ bcur2,
            unsigned* __restrict__ tmp1, ushort* __restrict__ tmp2, int nE) {
    __shared__ unsigned hist[256], scanT[256], lcur[256], base[256];
    __shared__ unsigned stag4[PCH];      // 16 KB
    __shared__ uchar    stagB[PCH];      // 4 KB (phase 1 only)
    int t = threadIdx.x;
    int e0 = blockIdx.x * PCH;
    int e1 = min(e0 + PCH, nE);
    int cntE = e1 - e0;

    int sv[PIT], dv[PIT];
    // ---------------- phase 1: dst ----------------
    if (t < 256) hist[t] = 0;
    __syncthreads();
    #pragma unroll
    for (int m = 0; m < PIT; ++m) {
        int e = e0 + t + m * PTH;
        if (e < e1) {
            sv[m] = src[e]; dv[m] = dst[e];
            atomicAdd(&hist[dv[m] >> BSH], 1u);
        }
    }
    __syncthreads();
    unsigned v = (t < 256) ? hist[t] : 0u;
    if (t < 256) scanT[t] = v;
    __syncthreads();
    for (int off = 1; off < 256; off <<= 1) {
        unsigned add = (t < 256 && t >= off) ? scanT[t - off] : 0u;
        __syncthreads();
        if (t < 256) scanT[t] += add;
        __syncthreads();
    }
    if (t < 256) {
        unsigned excl = scanT[t] - v;
        lcur[t] = excl;
        if (v > 0) { unsigned g = atomicAdd(&bcur1[t], v); base[t] = (unsigned)t * CAP + g - excl; }
    }
    __syncthreads();
    #pragma unroll
    for (int m = 0; m < PIT; ++m) {
        int e = e0 + t + m * PTH;
        if (e < e1) {
            int d = dv[m], s = sv[m];
            int b = d >> BSH;
            unsigned p = atomicAdd(&lcur[b], 1u);
            stag4[p] = ((unsigned)(d & (BSZ - 1)) << 17) | (unsigned)s;
            stagB[p] = (uchar)b;
        }
    }
    __syncthreads();
    for (int i = t; i < cntE; i += PTH) {
        unsigned b = stagB[i];
        unsigned a = base[b] + (unsigned)i;
        if (a < (b + 1u) * CAP) tmp1[a] = stag4[i];
    }
    __syncthreads();

    // ---------------- phase 2: src ----------------
    if (t < 256) hist[t] = 0;
    __syncthreads();
    #pragma unroll
    for (int m = 0; m < PIT; ++m) {
        int e = e0 + t + m * PTH;
        if (e < e1) atomicAdd(&hist[sv[m] >> BSH], 1u);
    }
    __syncthreads();
    v = (t < 256) ? hist[t] : 0u;
    if (t < 256) scanT[t] = v;
    __syncthreads();
    for (int off = 1; off < 256; off <<= 1) {
        unsigned add = (t < 256 && t >= off) ? scanT[t - off] : 0u;
        __syncthreads();
        if (t < 256) scanT[t] += add;
        __syncthreads();
    }
    if (t < 256) {
        unsigned excl = scanT[t] - v;
        lcur[t] = excl;
        if (v > 0) { unsigned g = atomicAdd(&bcur2[t], v); base[t] = (unsigned)t * CAP + g - excl; }
    }
    __syncthreads();
    #pragma unroll
    for (int m = 0; m < PIT; ++m) {
        int e = e0 + t + m * PTH;
        if (e < e1) {
            int s = sv[m];
            unsigned p = atomicAdd(&lcur[s >> BSH], 1u);
            stag4[p] = (unsigned)s;
        }
    }
    __syncthreads();
    for (int i = t; i < cntE; i += PTH) {
        unsigned s = stag4[i];
        unsigned b = s >> BSH;
        unsigned a = base[b] + (unsigned)i;
        if (a < (b + 1u) * CAP) tmp2[a] = (ushort)(s & (BSZ - 1));
    }
}

// ------- per bucket: count indeg/outdeg in LDS, emit ns / hs0 / nd.
//         NO scan, NO sort, NO csr.
__global__ __launch_bounds__(1024)
void k_cnt(const unsigned* __restrict__ bcur1, const unsigned* __restrict__ tmp1,
           const unsigned* __restrict__ bcur2, const ushort* __restrict__ tmp2,
           float* __restrict__ ns, float* __restrict__ hs0, float* __restrict__ ndv) {
    __shared__ unsigned cin[BSZ], cout[BSZ];
    int b = blockIdx.x, t = threadIdx.x;
    if (t < BSZ) { cin[t] = 0; cout[t] = 0; }
    __syncthreads();
    unsigned f1 = min(bcur1[b], (unsigned)CAP);
    const unsigned* tp1 = tmp1 + (size_t)b * CAP;
    for (unsigned i = t; i < f1; i += 1024) atomicAdd(&cin[tp1[i] >> 17], 1u);
    unsigned f2 = min(bcur2[b], (unsigned)CAP);
    const ushort* tp2 = tmp2 + (size_t)b * CAP;
    for (unsigned i = t; i < f2; i += 1024) atomicAdd(&cout[tp2[i]], 1u);
    __syncthreads();
    if (t < BSZ) {
        int n = b * BSZ + t;
        if (n < N_NODES) {
            unsigned ci = cin[t];
            float nsv = rsqrtf(fmaxf((float)cout[t], 1.0f));
            ns[n]  = nsv;
            hs0[n] = (float)ci * nsv;                  // h0 = indeg; hs0 = h0*norm_src
            ndv[n] = rsqrtf(fmaxf((float)ci, 1.0f));   // norm_dst
        }
    }
}

// ---- conv1 agg per bucket via LDS float atomics + node info; U/V table in blocks<129
__global__ __launch_bounds__(512)
void k_info(const unsigned* __restrict__ bcur1, const unsigned* __restrict__ tmp1,
            const float* __restrict__ hs0, const float* __restrict__ ns,
            const float* __restrict__ ndv,
            const float* __restrict__ W1, const float* __restrict__ b1,
            const float* __restrict__ W2,
            float* __restrict__ U, float* __restrict__ V,
            float4* __restrict__ info) {
    __shared__ float agg[BSZ];
    __shared__ float stu[128];        // unsorted breakpoints
    __shared__ float sts[128];        // sorted (blocks < 129 only)
    int b = blockIdx.x, t = threadIdx.x;
    agg[t] = 0.0f;
    if (t < 128) {
        float w = W1[t], bb = b1[t];
        stu[t] = (w != 0.0f) ? (-bb / w) : 1e30f;
    }
    __syncthreads();
    if (b < 129) {                    // block-uniform branch: syncs legal
        if (t < 128) sts[t] = stu[t];
        __syncthreads();
        for (int k = 2; k <= 128; k <<= 1) {
            for (int j = k >> 1; j > 0; j >>= 1) {
                if (t < 128) {
                    int ixj = t ^ j;
                    if (ixj > t) {
                        float a = sts[t], bb = sts[ixj];
                        bool up = ((t & k) == 0);
                        if (up ? (a > bb) : (a < bb)) { sts[t] = bb; sts[ixj] = a; }
                    }
                }
                __syncthreads();
            }
        }
        if (t < 128) {                // segment-table row, unconditional W2 loads
            int sg = b;
            float a_rep;
            if (sg == 0)        a_rep = sts[0]   - 1.0f;
            else if (sg == 128) a_rep = sts[127] + 1.0f;
            else                a_rep = 0.5f * (sts[sg - 1] + sts[sg]);
            float u = 0.0f, vv = 0.0f;
            #pragma unroll 8
            for (int j = 0; j < 128; ++j) {
                float w  = W1[j], bb = b1[j];
                float w2 = W2[j * HIDDEN + t];
                bool on  = (a_rep * w + bb > 0.0f);
                u  += on ? w  * w2 : 0.0f;
                vv += on ? bb * w2 : 0.0f;
            }
            U[sg * HIDDEN + t] = u;
            V[sg * HIDDEN + t] = vv;
        }
    }
    // edge accumulate: agg[dl] += hs0[src]
    unsigned f1 = min(bcur1[b], (unsigned)CAP);
    const unsigned* tp1 = tmp1 + (size_t)b * CAP;
    for (unsigned i = t; i < f1; i += 512) {
        unsigned e = tp1[i];
        atomicAdd(&agg[e >> 17], hs0[e & 0x1FFFFu]);
    }
    __syncthreads();
    int n = b * BSZ + t;
    if (n < N_NODES) {
        float nd = ndv[n];
        float av = agg[t] * nd;
        int sgp = 0;
        #pragma unroll 16
        for (int q = 0; q < 128; ++q) sgp += (stu[q] < av) ? 1 : 0;
        float nsv = ns[n];
        info[n] = make_float4(nsv * av, nsv, __int_as_float(sgp), nd);
    }
}

// ---- conv2 per bucket: LDS accumulate (A,B,min/max sg) over edges, then
//      rows + flush-on-change pooling (graph_ids sorted). Mixed nodes rescan.
__global__ __launch_bounds__(512)
void k_conv2(const unsigned* __restrict__ bcur1, const unsigned* __restrict__ tmp1,
             const float4* __restrict__ info,
             const float* __restrict__ U, const float* __restrict__ V,
             const int* __restrict__ graph_ids, const float* __restrict__ b2,
             float* __restrict__ pool, float* __restrict__ cnt) {
    __shared__ float aggA[BSZ], aggB[BSZ];
    __shared__ uint  smn[BSZ], smx[BSZ];
    int b = blockIdx.x, t = threadIdx.x;
    aggA[t] = 0.0f; aggB[t] = 0.0f; smn[t] = 255u; smx[t] = 0u;
    __syncthreads();
    unsigned f1 = min(bcur1[b], (unsigned)CAP);
    const unsigned* tp1 = tmp1 + (size_t)b * CAP;
    for (unsigned i = t; i < f1; i += 512) {
        unsigned e = tp1[i];
        unsigned dl = e >> 17;
        float4 nf = info[e & 0x1FFFFu];
        atomicAdd(&aggA[dl], nf.x);
        atomicAdd(&aggB[dl], nf.y);
        uint sg = (uint)__float_as_int(nf.z);
        atomicMin(&smn[dl], sg);
        atomicMax(&smx[dl], sg);
    }
    __syncthreads();

    int d = t & 127, q = t >> 7;           // 4 node-groups x 128 dims
    float bbd = b2[d];
    int base = b * BSZ;
    int nmax = min(BSZ, N_NODES - base);
    int gcur = -1; float racc = 0.0f, cl = 0.0f;
    for (int i = q; i < nmax; i += 4) {
        int n = base + i;
        uint mn = smn[i], mx = smx[i];
        float acc;
        if (mn >= mx) {                    // uniform segment (or no edges)
            uint sg = min(mn, 128u);
            acc = aggA[i] * U[sg * HIDDEN + d] + aggB[i] * V[sg * HIDDEN + d];
        } else {                           // mixed: exact rescan of bucket edges (rare)
            acc = 0.0f;
            for (unsigned k = 0; k < f1; ++k) {
                unsigned e = tp1[k];
                if ((e >> 17) == (unsigned)i) {
                    float4 nf = info[e & 0x1FFFFu];
                    uint sg = (uint)__float_as_int(nf.z);
                    acc += nf.x * U[sg * HIDDEN + d] + nf.y * V[sg * HIDDEN + d];
                }
            }
        }
        float nd = info[n].w;
        float row = fmaxf(nd * acc + bbd, 0.0f);
        int g = graph_ids[n];
        if (g != gcur) {
            if (gcur >= 0) {
                atomicAdd(&pool[gcur * HIDDEN + d], racc);
                if (d == 0) atomicAdd(&cnt[gcur], cl);
            }
            gcur = g; racc = 0.0f; cl = 0.0f;
        }
        racc += row; cl += 1.0f;
    }
    if (gcur >= 0) {
        atomicAdd(&pool[gcur * HIDDEN + d], racc);
        if (d == 0) atomicAdd(&cnt[gcur], cl);
    }
}

// ----------------------------------------------- classifier head (tiny)
__global__ void k_final(const float* __restrict__ pool, const float* __restrict__ cnt,
                        const float* __restrict__ Wc, const float* __restrict__ bc,
                        float* __restrict__ out) {
    int t = blockIdx.x * blockDim.x + threadIdx.x;
    if (t >= N_GRAPHS * N_CLASSES) return;
    int g = t / N_CLASSES, c = t % N_CLASSES;
    float inv = 1.0f / fmaxf(cnt[g], 1.0f);
    float acc = bc[c];
    for (int j = 0; j < HIDDEN; ++j)
        acc += pool[g * HIDDEN + j] * inv * Wc[j * N_CLASSES + c];
    out[t] = acc;
}

extern "C" void kernel_launch(void* const* d_in, const int* in_sizes, int n_in,
                              void* d_out, int out_size, void* d_ws, size_t ws_size,
                              hipStream_t stream) {
    const int*   src       = (const int*)d_in[0];
    const int*   dst       = (const int*)d_in[1];
    const int*   graph_ids = (const int*)d_in[2];
    const float* W1        = (const float*)d_in[3];
    const float* b1        = (const float*)d_in[4];
    const float* W2        = (const float*)d_in[5];
    const float* b2        = (const float*)d_in[6];
    const float* Wc        = (const float*)d_in[7];
    const float* bc        = (const float*)d_in[8];
    float* out = (float*)d_out;

    char* ws = (char*)d_ws;
    size_t off = 0;
    auto alloc = [&](size_t elems) { void* p = ws + off; off += elems * 4; return p; };

    // --- zeroed region (single small memset) ---
    unsigned* bcur1 = (unsigned*)alloc(256);
    unsigned* bcur2 = (unsigned*)alloc(256);
    float*    pool  = (float*)   alloc(N_GRAPHS * HIDDEN);   // 64 KB
    float*    cnt   = (float*)   alloc(N_GRAPHS);
    size_t zero_bytes = off;                                 // ~68 KB
    // --- non-zeroed ---
    float4*   info  = (float4*)  alloc((size_t)N_NODES * 4); // 1.6 MB (16B-aligned)
    unsigned* tmp1  = (unsigned*)alloc((size_t)NBUCK * CAP); // 12.8 MB
    ushort*   tmp2  = (ushort*)  alloc((size_t)NBUCK * CAP / 2); // 6.4 MB
    float*    nsA   = (float*)   alloc(N_NODES);
    float*    hs0   = (float*)   alloc(N_NODES);
    float*    ndv   = (float*)   alloc(N_NODES);
    float*    U     = (float*)   alloc(129 * HIDDEN);
    float*    V     = (float*)   alloc(129 * HIDDEN);

    hipMemsetAsync(d_ws, 0, zero_bytes, stream);

    int pblocks = (N_EDGES + PCH - 1) / PCH;    // 391
    k_part <<<pblocks, PTH, 0, stream>>>(src, dst, bcur1, bcur2, tmp1, tmp2, N_EDGES);
    k_cnt  <<<NBUCK, 1024, 0, stream>>>(bcur1, tmp1, bcur2, tmp2, nsA, hs0, ndv);
    k_info <<<NBUCK, 512, 0, stream>>>(bcur1, tmp1, hs0, nsA, ndv, W1, b1, W2, U, V, info);
    k_conv2<<<NBUCK, 512, 0, stream>>>(bcur1, tmp1, info, U, V, graph_ids, b2, pool, cnt);
    k_final<<<(N_GRAPHS * N_CLASSES + 255) / 256, 256, 0, stream>>>(pool, cnt, Wc, bc, out);
}

// Round 3
// 175.019 us; speedup vs baseline: 2.3563x; 1.0876x over previous
//
#include <hip/hip_runtime.h>

#define N_NODES   100000
#define N_EDGES   1600000
#define N_GRAPHS  128
#define HIDDEN    128
#define N_CLASSES 10

#define BSH   8                   // bucket = 256 nodes
#define BSZ   256
#define NBUCK 391                 // ceil(100000/256)
#define NBIN  512                 // histogram bins (>= NBUCK)
#define CAP   8192                // mean fill 4096, huge headroom
#define PCH   4096                // edges per partition block
#define PTH   512                 // partition threads
#define PIT   (PCH / PTH)         // 8 edges cached per thread

typedef unsigned int   uint;
typedef unsigned short ushort;

// ---- 512-wide exclusive scan: wave shfl scan + tiny cross-wave fixup (2 syncs)
__device__ __forceinline__ uint scan_excl_512(uint v, int t, uint* wtmp) {
    uint lane = (uint)(t & 63);
    uint incl = v;
    #pragma unroll
    for (int off = 1; off < 64; off <<= 1) {
        uint up = __shfl_up(incl, off, 64);
        if (lane >= (uint)off) incl += up;
    }
    if (lane == 63) wtmp[t >> 6] = incl;
    __syncthreads();
    uint wo = 0;
    int w = t >> 6;
    #pragma unroll
    for (int k = 0; k < 7; ++k) wo += (k < w) ? wtmp[k] : 0u;
    __syncthreads();                 // wtmp reusable by next call
    return incl + wo - v;
}

// -------- partition, two sequential phases sharing one staging buffer;
//          src/dst register-cached across phases. 512 bins, wave-scan.
__global__ __launch_bounds__(PTH)
void k_part(const int* __restrict__ src, const int* __restrict__ dst,
            uint* __restrict__ bcur1, uint* __restrict__ bcur2,
            uint* __restrict__ tmp1, ushort* __restrict__ tmp2, int nE) {
    __shared__ uint   hist[NBIN], lcur[NBIN], base[NBIN];
    __shared__ uint   wtmp[8];
    __shared__ uint   stag4[PCH];        // 16 KB
    __shared__ ushort stagB[PCH];        // 8 KB (phase 1 only)
    int t = threadIdx.x;
    int e0 = blockIdx.x * PCH;
    int e1 = min(e0 + PCH, nE);
    int cntE = e1 - e0;

    int sv[PIT], dv[PIT];
    // ---------------- phase 1: dst ----------------
    hist[t] = 0;                         // NBIN == PTH
    __syncthreads();
    #pragma unroll
    for (int m = 0; m < PIT; ++m) {
        int e = e0 + t + m * PTH;
        if (e < e1) {
            sv[m] = src[e]; dv[m] = dst[e];
            atomicAdd(&hist[dv[m] >> BSH], 1u);
        }
    }
    __syncthreads();
    uint v = hist[t];
    uint excl = scan_excl_512(v, t, wtmp);
    lcur[t] = excl;
    if (v > 0) { uint g = atomicAdd(&bcur1[t], v); base[t] = (uint)t * CAP + g - excl; }
    __syncthreads();
    #pragma unroll
    for (int m = 0; m < PIT; ++m) {
        int e = e0 + t + m * PTH;
        if (e < e1) {
            int d = dv[m], s = sv[m];
            int b = d >> BSH;
            uint p = atomicAdd(&lcur[b], 1u);
            stag4[p] = ((uint)(d & (BSZ - 1)) << 17) | (uint)s;
            stagB[p] = (ushort)b;
        }
    }
    __syncthreads();
    for (int i = t; i < cntE; i += PTH) {
        uint b = stagB[i];
        uint a = base[b] + (uint)i;
        if (a < (b + 1u) * CAP) tmp1[a] = stag4[i];
    }
    __syncthreads();

    // ---------------- phase 2: src ----------------
    hist[t] = 0;
    __syncthreads();
    #pragma unroll
    for (int m = 0; m < PIT; ++m) {
        int e = e0 + t + m * PTH;
        if (e < e1) atomicAdd(&hist[sv[m] >> BSH], 1u);
    }
    __syncthreads();
    v = hist[t];
    excl = scan_excl_512(v, t, wtmp);
    lcur[t] = excl;
    if (v > 0) { uint g = atomicAdd(&bcur2[t], v); base[t] = (uint)t * CAP + g - excl; }
    __syncthreads();
    #pragma unroll
    for (int m = 0; m < PIT; ++m) {
        int e = e0 + t + m * PTH;
        if (e < e1) {
            int s = sv[m];
            uint p = atomicAdd(&lcur[s >> BSH], 1u);
            stag4[p] = (uint)s;
        }
    }
    __syncthreads();
    for (int i = t; i < cntE; i += PTH) {
        uint s = stag4[i];
        uint b = s >> BSH;
        uint a = base[b] + (uint)i;
        if (a < (b + 1u) * CAP) tmp2[a] = (ushort)(s & (BSZ - 1));
    }
}

// ------- per bucket: count indeg/outdeg in LDS, emit ns / hs0 / nd.
__global__ __launch_bounds__(1024)
void k_cnt(const uint* __restrict__ bcur1, const uint* __restrict__ tmp1,
           const uint* __restrict__ bcur2, const ushort* __restrict__ tmp2,
           float* __restrict__ ns, float* __restrict__ hs0, float* __restrict__ ndv) {
    __shared__ uint cin[BSZ], cout[BSZ];
    int b = blockIdx.x, t = threadIdx.x;
    if (t < BSZ) { cin[t] = 0; cout[t] = 0; }
    __syncthreads();
    uint f1 = min(bcur1[b], (uint)CAP);
    const uint* tp1 = tmp1 + (size_t)b * CAP;
    uint i = t;
    for (; i + 3072u < f1; i += 4096u) {
        uint a0 = tp1[i], a1 = tp1[i + 1024], a2 = tp1[i + 2048], a3 = tp1[i + 3072];
        atomicAdd(&cin[a0 >> 17], 1u); atomicAdd(&cin[a1 >> 17], 1u);
        atomicAdd(&cin[a2 >> 17], 1u); atomicAdd(&cin[a3 >> 17], 1u);
    }
    for (; i < f1; i += 1024u) atomicAdd(&cin[tp1[i] >> 17], 1u);
    uint f2 = min(bcur2[b], (uint)CAP);
    const ushort* tp2 = tmp2 + (size_t)b * CAP;
    i = t;
    for (; i + 3072u < f2; i += 4096u) {
        uint a0 = tp2[i], a1 = tp2[i + 1024], a2 = tp2[i + 2048], a3 = tp2[i + 3072];
        atomicAdd(&cout[a0], 1u); atomicAdd(&cout[a1], 1u);
        atomicAdd(&cout[a2], 1u); atomicAdd(&cout[a3], 1u);
    }
    for (; i < f2; i += 1024u) atomicAdd(&cout[tp2[i]], 1u);
    __syncthreads();
    if (t < BSZ) {
        int n = b * BSZ + t;
        if (n < N_NODES) {
            uint ci = cin[t];
            float nsv = rsqrtf(fmaxf((float)cout[t], 1.0f));
            ns[n]  = nsv;
            hs0[n] = (float)ci * nsv;                  // h0 = indeg; hs0 = h0*norm_src
            ndv[n] = rsqrtf(fmaxf((float)ci, 1.0f));   // norm_dst
        }
    }
}

// ---- conv1 agg per bucket via LDS float atomics + node info; U/V table in blocks<129
__global__ __launch_bounds__(1024)
void k_info(const uint* __restrict__ bcur1, const uint* __restrict__ tmp1,
            const float* __restrict__ hs0, const float* __restrict__ ns,
            const float* __restrict__ ndv,
            const float* __restrict__ W1, const float* __restrict__ b1,
            const float* __restrict__ W2,
            float* __restrict__ U, float* __restrict__ V,
            float4* __restrict__ info) {
    __shared__ float agg[BSZ];
    __shared__ float stu[128];        // unsorted breakpoints
    __shared__ float sts[128];        // sorted (blocks < 129 only)
    int b = blockIdx.x, t = threadIdx.x;
    if (t < BSZ) agg[t] = 0.0f;
    if (t < 128) {
        float w = W1[t], bb = b1[t];
        stu[t] = (w != 0.0f) ? (-bb / w) : 1e30f;
    }
    __syncthreads();
    if (b < 129) {                    // block-uniform branch: syncs legal
        if (t < 128) sts[t] = stu[t];
        __syncthreads();
        for (int k = 2; k <= 128; k <<= 1) {
            for (int j = k >> 1; j > 0; j >>= 1) {
                if (t < 128) {
                    int ixj = t ^ j;
                    if (ixj > t) {
                        float a = sts[t], bb = sts[ixj];
                        bool up = ((t & k) == 0);
                        if (up ? (a > bb) : (a < bb)) { sts[t] = bb; sts[ixj] = a; }
                    }
                }
                __syncthreads();
            }
        }
        if (t < 128) {                // segment-table row, unconditional W2 loads
            int sg = b;
            float a_rep;
            if (sg == 0)        a_rep = sts[0]   - 1.0f;
            else if (sg == 128) a_rep = sts[127] + 1.0f;
            else                a_rep = 0.5f * (sts[sg - 1] + sts[sg]);
            float u = 0.0f, vv = 0.0f;
            #pragma unroll 8
            for (int j = 0; j < 128; ++j) {
                float w  = W1[j], bb = b1[j];
                float w2 = W2[j * HIDDEN + t];
                bool on  = (a_rep * w + bb > 0.0f);
                u  += on ? w  * w2 : 0.0f;
                vv += on ? bb * w2 : 0.0f;
            }
            U[sg * HIDDEN + t] = u;
            V[sg * HIDDEN + t] = vv;
        }
    }
    // edge accumulate: agg[dl] += hs0[src], 4-way MLP
    uint f1 = min(bcur1[b], (uint)CAP);
    const uint* tp1 = tmp1 + (size_t)b * CAP;
    uint i = t;
    for (; i + 3072u < f1; i += 4096u) {
        uint e0 = tp1[i], e1 = tp1[i + 1024], e2 = tp1[i + 2048], e3 = tp1[i + 3072];
        float h0 = hs0[e0 & 0x1FFFFu], h1 = hs0[e1 & 0x1FFFFu];
        float h2 = hs0[e2 & 0x1FFFFu], h3 = hs0[e3 & 0x1FFFFu];
        atomicAdd(&agg[e0 >> 17], h0); atomicAdd(&agg[e1 >> 17], h1);
        atomicAdd(&agg[e2 >> 17], h2); atomicAdd(&agg[e3 >> 17], h3);
    }
    for (; i < f1; i += 1024u) {
        uint e = tp1[i];
        atomicAdd(&agg[e >> 17], hs0[e & 0x1FFFFu]);
    }
    __syncthreads();
    int n = b * BSZ + t;
    if (t < BSZ && n < N_NODES) {
        float nd = ndv[n];
        float av = agg[t] * nd;
        int sgp = 0;
        #pragma unroll 16
        for (int q = 0; q < 128; ++q) sgp += (stu[q] < av) ? 1 : 0;
        float nsv = ns[n];
        info[n] = make_float4(nsv * av, nsv, __int_as_float(sgp), nd);
    }
}

// ---- conv2 per bucket: LDS accumulate (A,B,min/max sg) over edges, 4-way MLP,
//      then rows + flush-on-change pooling (graph_ids sorted). Mixed nodes rescan.
__global__ __launch_bounds__(1024)
void k_conv2(const uint* __restrict__ bcur1, const uint* __restrict__ tmp1,
             const float4* __restrict__ info, const float* __restrict__ ndv,
             const float* __restrict__ U, const float* __restrict__ V,
             const int* __restrict__ graph_ids, const float* __restrict__ b2,
             float* __restrict__ pool, float* __restrict__ cnt) {
    __shared__ float aggA[BSZ], aggB[BSZ];
    __shared__ uint  smn[BSZ], smx[BSZ];
    int b = blockIdx.x, t = threadIdx.x;
    if (t < BSZ) { aggA[t] = 0.0f; aggB[t] = 0.0f; smn[t] = 255u; smx[t] = 0u; }
    __syncthreads();
    uint f1 = min(bcur1[b], (uint)CAP);
    const uint* tp1 = tmp1 + (size_t)b * CAP;
    uint i = t;
    for (; i + 3072u < f1; i += 4096u) {
        uint e0 = tp1[i], e1 = tp1[i + 1024], e2 = tp1[i + 2048], e3 = tp1[i + 3072];
        float4 n0 = info[e0 & 0x1FFFFu];
        float4 n1 = info[e1 & 0x1FFFFu];
        float4 n2 = info[e2 & 0x1FFFFu];
        float4 n3 = info[e3 & 0x1FFFFu];
        uint d0 = e0 >> 17, d1 = e1 >> 17, d2 = e2 >> 17, d3 = e3 >> 17;
        atomicAdd(&aggA[d0], n0.x); atomicAdd(&aggB[d0], n0.y);
        atomicAdd(&aggA[d1], n1.x); atomicAdd(&aggB[d1], n1.y);
        atomicAdd(&aggA[d2], n2.x); atomicAdd(&aggB[d2], n2.y);
        atomicAdd(&aggA[d3], n3.x); atomicAdd(&aggB[d3], n3.y);
        uint s0 = (uint)__float_as_int(n0.z), s1 = (uint)__float_as_int(n1.z);
        uint s2 = (uint)__float_as_int(n2.z), s3 = (uint)__float_as_int(n3.z);
        atomicMin(&smn[d0], s0); atomicMax(&smx[d0], s0);
        atomicMin(&smn[d1], s1); atomicMax(&smx[d1], s1);
        atomicMin(&smn[d2], s2); atomicMax(&smx[d2], s2);
        atomicMin(&smn[d3], s3); atomicMax(&smx[d3], s3);
    }
    for (; i < f1; i += 1024u) {
        uint e = tp1[i];
        uint dl = e >> 17;
        float4 nf = info[e & 0x1FFFFu];
        atomicAdd(&aggA[dl], nf.x);
        atomicAdd(&aggB[dl], nf.y);
        uint sg = (uint)__float_as_int(nf.z);
        atomicMin(&smn[dl], sg);
        atomicMax(&smx[dl], sg);
    }
    __syncthreads();

    int d = t & 127, q = t >> 7;           // 8 node-groups x 128 dims
    float bbd = b2[d];
    int base = b * BSZ;
    int nmax = min(BSZ, N_NODES - base);
    int gcur = -1; float racc = 0.0f, cl = 0.0f;
    for (int r = q; r < nmax; r += 8) {
        int n = base + r;
        uint mn = smn[r], mx = smx[r];
        float acc;
        if (mn >= mx) {                    // uniform segment (or no edges)
            uint sg = min(mn, 128u);
            acc = aggA[r] * U[sg * HIDDEN + d] + aggB[r] * V[sg * HIDDEN + d];
        } else {                           // mixed: exact rescan of bucket edges (rare)
            acc = 0.0f;
            for (uint k = 0; k < f1; ++k) {
                uint e = tp1[k];
                if ((e >> 17) == (uint)r) {
                    float4 nf = info[e & 0x1FFFFu];
                    uint sg = (uint)__float_as_int(nf.z);
                    acc += nf.x * U[sg * HIDDEN + d] + nf.y * V[sg * HIDDEN + d];
                }
            }
        }
        float nd = ndv[n];
        float row = fmaxf(nd * acc + bbd, 0.0f);
        int g = graph_ids[n];
        if (g != gcur) {
            if (gcur >= 0) {
                atomicAdd(&pool[gcur * HIDDEN + d], racc);
                if (d == 0) atomicAdd(&cnt[gcur], cl);
            }
            gcur = g; racc = 0.0f; cl = 0.0f;
        }
        racc += row; cl += 1.0f;
    }
    if (gcur >= 0) {
        atomicAdd(&pool[gcur * HIDDEN + d], racc);
        if (d == 0) atomicAdd(&cnt[gcur], cl);
    }
}

// ----------------------------------------------- classifier head (tiny)
__global__ void k_final(const float* __restrict__ pool, const float* __restrict__ cnt,
                        const float* __restrict__ Wc, const float* __restrict__ bc,
                        float* __restrict__ out) {
    int t = blockIdx.x * blockDim.x + threadIdx.x;
    if (t >= N_GRAPHS * N_CLASSES) return;
    int g = t / N_CLASSES, c = t % N_CLASSES;
    float inv = 1.0f / fmaxf(cnt[g], 1.0f);
    float acc = bc[c];
    for (int j = 0; j < HIDDEN; ++j)
        acc += pool[g * HIDDEN + j] * inv * Wc[j * N_CLASSES + c];
    out[t] = acc;
}

extern "C" void kernel_launch(void* const* d_in, const int* in_sizes, int n_in,
                              void* d_out, int out_size, void* d_ws, size_t ws_size,
                              hipStream_t stream) {
    const int*   src       = (const int*)d_in[0];
    const int*   dst       = (const int*)d_in[1];
    const int*   graph_ids = (const int*)d_in[2];
    const float* W1        = (const float*)d_in[3];
    const float* b1        = (const float*)d_in[4];
    const float* W2        = (const float*)d_in[5];
    const float* b2        = (const float*)d_in[6];
    const float* Wc        = (const float*)d_in[7];
    const float* bc        = (const float*)d_in[8];
    float* out = (float*)d_out;

    char* ws = (char*)d_ws;
    size_t off = 0;
    auto alloc = [&](size_t elems) { void* p = ws + off; off += elems * 4; return p; };

    // --- zeroed region (single small memset) ---
    uint*  bcur1 = (uint*) alloc(NBIN);
    uint*  bcur2 = (uint*) alloc(NBIN);
    float* pool  = (float*)alloc(N_GRAPHS * HIDDEN);        // 64 KB
    float* cnt   = (float*)alloc(N_GRAPHS);
    size_t zero_bytes = off;                                // ~70 KB
    // --- non-zeroed ---
    float4* info = (float4*)alloc((size_t)N_NODES * 4);     // 1.6 MB (16B-aligned)
    uint*   tmp1 = (uint*)  alloc((size_t)NBUCK * CAP);     // 12.8 MB
    ushort* tmp2 = (ushort*)alloc((size_t)NBUCK * CAP / 2); // 6.4 MB
    float*  nsA  = (float*) alloc(N_NODES);
    float*  hs0  = (float*) alloc(N_NODES);
    float*  ndv  = (float*) alloc(N_NODES);
    float*  U    = (float*) alloc(129 * HIDDEN);
    float*  V    = (float*) alloc(129 * HIDDEN);

    hipMemsetAsync(d_ws, 0, zero_bytes, stream);

    int pblocks = (N_EDGES + PCH - 1) / PCH;    // 391
    k_part <<<pblocks, PTH, 0, stream>>>(src, dst, bcur1, bcur2, tmp1, tmp2, N_EDGES);
    k_cnt  <<<NBUCK, 1024, 0, stream>>>(bcur1, tmp1, bcur2, tmp2, nsA, hs0, ndv);
    k_info <<<NBUCK, 1024, 0, stream>>>(bcur1, tmp1, hs0, nsA, ndv, W1, b1, W2, U, V, info);
    k_conv2<<<NBUCK, 1024, 0, stream>>>(bcur1, tmp1, info, ndv, U, V, graph_ids, b2, pool, cnt);
    k_final<<<(N_GRAPHS * N_CLASSES + 255) / 256, 256, 0, stream>>>(pool, cnt, Wc, bc, out);
}